// Round 1
// baseline (708.737 us; speedup 1.0000x reference)
//
#include <hip/hip_runtime.h>
#include <cstdint>
#include <cstddef>

#define HD   1024
#define SEQL 200
#define MEMN 50
#define RTOT 51200   // 256 * 200

typedef float  f4    __attribute__((ext_vector_type(4)));
typedef float  f32x4 __attribute__((ext_vector_type(4)));
typedef short  s16x8 __attribute__((ext_vector_type(8)));
typedef unsigned short u16;
typedef unsigned short u16x4 __attribute__((ext_vector_type(4)));

__device__ __forceinline__ u16 f2bf(float f) {
    unsigned u = __builtin_bit_cast(unsigned, f);
    u += 0x7FFFu + ((u >> 16) & 1u);          // RNE
    return (u16)(u >> 16);
}
__device__ __forceinline__ float bf2f(u16 h) {
    unsigned u = ((unsigned)h) << 16;
    return __builtin_bit_cast(float, u);
}

#define GLOAD_LDS16(g, l) __builtin_amdgcn_global_load_lds( \
    (const __attribute__((address_space(1))) unsigned int*)(g), \
    (__attribute__((address_space(3))) unsigned int*)(l), 16, 0, 0)

// ---------------------------------------------------------------------------
// K0: gate_w f32 -> bf16 (layout preserved: [o][2048], K-contiguous)
// ---------------------------------------------------------------------------
__global__ __launch_bounds__(256) void k_cvt_w(const float* __restrict__ gw,
                                               u16* __restrict__ gwB)
{
    const size_t i = ((size_t)blockIdx.x * 256 + threadIdx.x) * 8;
    f4 v0 = *(const f4*)&gw[i];
    f4 v1 = *(const f4*)&gw[i + 4];
    u16x4 b0 = { f2bf(v0.x), f2bf(v0.y), f2bf(v0.z), f2bf(v0.w) };
    u16x4 b1 = { f2bf(v1.x), f2bf(v1.y), f2bf(v1.z), f2bf(v1.w) };
    *(u16x4*)&gwB[i]     = b0;
    *(u16x4*)&gwB[i + 4] = b1;
}

// ---------------------------------------------------------------------------
// K1: feats = x + pos  (store bf16);  sim = feats @ mem^T in f32;
//     softmax over 50;  mem_read = w @ mem  (store bf16).
//     64 rows per block, 256 threads. tx = tid&15 (m-dir), ty = tid>>4 (rows).
// ---------------------------------------------------------------------------
__global__ __launch_bounds__(256) void k_feats_mem(
    const float* __restrict__ x, const float* __restrict__ smem,
    const float* __restrict__ pos, u16* __restrict__ featsB,
    u16* __restrict__ memrB)
{
    __shared__ float fP[64][68];   // feats k-panel (pad 68 -> conflict-free)
    __shared__ float mP[64][68];   // memory k-panel (rows 50..63 zero)
    __shared__ float wL[64][52];   // softmax weights

    const int tid = threadIdx.x;
    const int r0  = blockIdx.x * 64;
    const int tx  = tid & 15, ty = tid >> 4;

    float acc[4][4] = {};          // sim[row ty*4+i][m = tx + 16*j]

    for (int kp = 0; kp < HD; kp += 64) {
        // ---- stage feats panel (and emit bf16 feats) ----
        #pragma unroll
        for (int p = 0; p < 4; ++p) {
            const int r = (tid >> 4) + p * 16;
            const int c = (tid & 15) * 4;
            const int row = r0 + r;
            f4 xv = *(const f4*)&x[(size_t)row * HD + kp + c];
            f4 pv = *(const f4*)&pos[(size_t)(row % SEQL) * HD + kp + c];
            f4 fv = xv + pv;
            *(f4*)&fP[r][c] = fv;
            u16x4 fb = { f2bf(fv.x), f2bf(fv.y), f2bf(fv.z), f2bf(fv.w) };
            *(u16x4*)&featsB[(size_t)row * HD + kp + c] = fb;
        }
        // ---- stage memory panel (zero-pad rows >= 50) ----
        for (int idx = tid; idx < 64 * 16; idx += 256) {
            const int r = idx >> 4, c = (idx & 15) * 4;
            f4 v = {0.f, 0.f, 0.f, 0.f};
            if (r < MEMN) v = *(const f4*)&smem[(size_t)r * HD + kp + c];
            *(f4*)&mP[r][c] = v;
        }
        __syncthreads();

        // ---- sim accumulation: 4 rows x 4 m per thread ----
        #pragma unroll 4
        for (int k = 0; k < 64; k += 4) {
            f4 fv[4], mv[4];
            #pragma unroll
            for (int i = 0; i < 4; ++i) fv[i] = *(const f4*)&fP[ty * 4 + i][k];
            #pragma unroll
            for (int j = 0; j < 4; ++j) mv[j] = *(const f4*)&mP[tx + 16 * j][k];
            #pragma unroll
            for (int i = 0; i < 4; ++i)
                #pragma unroll
                for (int j = 0; j < 4; ++j)
                    acc[i][j] += fv[i].x * mv[j].x + fv[i].y * mv[j].y +
                                 fv[i].z * mv[j].z + fv[i].w * mv[j].w;
        }
        __syncthreads();
    }

    // ---- softmax over m (50), per row, across the 16 tx lanes ----
    #pragma unroll
    for (int i = 0; i < 4; ++i) {
        float mx = -1e30f;
        #pragma unroll
        for (int j = 0; j < 4; ++j) {
            const int m = tx + 16 * j;
            if (m < MEMN) mx = fmaxf(mx, acc[i][j]);
        }
        #pragma unroll
        for (int d = 1; d < 16; d <<= 1) mx = fmaxf(mx, __shfl_xor(mx, d, 16));
        float e[4]; float s = 0.f;
        #pragma unroll
        for (int j = 0; j < 4; ++j) {
            const int m = tx + 16 * j;
            e[j] = (m < MEMN) ? __expf(acc[i][j] - mx) : 0.f;
            s += e[j];
        }
        #pragma unroll
        for (int d = 1; d < 16; d <<= 1) s += __shfl_xor(s, d, 16);
        const float inv = 1.f / s;
        #pragma unroll
        for (int j = 0; j < 4; ++j) {
            const int m = tx + 16 * j;
            if (m < MEMN) wL[ty * 4 + i][m] = e[j] * inv;
        }
    }
    __syncthreads();

    // ---- mem_read = w @ mem ; each thread owns 4 contiguous columns ----
    const int c4 = tid * 4;
    for (int rg = 0; rg < 8; ++rg) {
        f4 a[8] = {};
        for (int m4 = 0; m4 < 48; m4 += 4) {
            f4 mv[4];
            #pragma unroll
            for (int q = 0; q < 4; ++q)
                mv[q] = *(const f4*)&smem[(size_t)(m4 + q) * HD + c4];
            #pragma unroll
            for (int r = 0; r < 8; ++r) {
                f4 wv = *(const f4*)&wL[rg * 8 + r][m4];
                a[r] += wv.x * mv[0] + wv.y * mv[1] + wv.z * mv[2] + wv.w * mv[3];
            }
        }
        f4 m48 = *(const f4*)&smem[(size_t)48 * HD + c4];
        f4 m49 = *(const f4*)&smem[(size_t)49 * HD + c4];
        #pragma unroll
        for (int r = 0; r < 8; ++r) {
            a[r] += wL[rg * 8 + r][48] * m48 + wL[rg * 8 + r][49] * m49;
            const int row = r0 + rg * 8 + r;
            u16x4 ob = { f2bf(a[r].x), f2bf(a[r].y), f2bf(a[r].z), f2bf(a[r].w) };
            *(u16x4*)&memrB[(size_t)row * HD + c4] = ob;
        }
    }
}

// ---------------------------------------------------------------------------
// K2: gate GEMM (M=51200, N=1024, K=2048 concat) + sigmoid + residual out.
//     m97 structure: 128x128 tile, BK=32, 4 waves (2x2), global_load_lds(16B).
// ---------------------------------------------------------------------------
__global__ __launch_bounds__(256) void k_gate_out(
    const u16* __restrict__ featsB, const u16* __restrict__ memrB,
    const u16* __restrict__ gwB, const float* __restrict__ gb,
    float* __restrict__ out)
{
    __shared__ u16 As[128 * 32];
    __shared__ u16 Bs[128 * 32];

    const int tid = threadIdx.x;
    int bid = blockIdx.x;
    bid = (bid & 7) * 400 + (bid >> 3);      // XCD swizzle (3200 % 8 == 0)
    const int mt = bid >> 3, nt = bid & 7;
    const int row0 = mt * 128, col0 = nt * 128;
    const int lane = tid & 63, wave = tid >> 6;
    const int wr = wave >> 1, wc = wave & 1;

    f32x4 acc[4][4] = {};

    const int sr = tid >> 2;                 // staging row 0..63
    const int sc = (tid & 3) * 8;            // staging col (elements)

    for (int kt = 0; kt < 64; ++kt) {
        const u16* Asrc = (kt < 32) ? featsB : memrB;
        const int kcol = (kt & 31) * 32;
        GLOAD_LDS16(Asrc + (size_t)(row0 + sr) * HD + kcol + sc,      &As[tid * 8]);
        GLOAD_LDS16(Asrc + (size_t)(row0 + 64 + sr) * HD + kcol + sc, &As[2048 + tid * 8]);
        GLOAD_LDS16(gwB + (size_t)(col0 + sr) * 2048 + kt * 32 + sc,      &Bs[tid * 8]);
        GLOAD_LDS16(gwB + (size_t)(col0 + 64 + sr) * 2048 + kt * 32 + sc, &Bs[2048 + tid * 8]);
        __syncthreads();

        s16x8 aF[4], bF[4];
        const int fr = lane & 15, fk = (lane >> 4) * 8;
        #pragma unroll
        for (int m = 0; m < 4; ++m)
            aF[m] = *(const s16x8*)&As[(wr * 64 + m * 16 + fr) * 32 + fk];
        #pragma unroll
        for (int n = 0; n < 4; ++n)
            bF[n] = *(const s16x8*)&Bs[(wc * 64 + n * 16 + fr) * 32 + fk];
        #pragma unroll
        for (int m = 0; m < 4; ++m)
            #pragma unroll
            for (int n = 0; n < 4; ++n)
                acc[m][n] = __builtin_amdgcn_mfma_f32_16x16x32_bf16(
                    aF[m], bF[n], acc[m][n], 0, 0, 0);
        __syncthreads();
    }

    // epilogue: out = feats + sigmoid(acc + b) * mem_read
    #pragma unroll
    for (int m = 0; m < 4; ++m) {
        #pragma unroll
        for (int n = 0; n < 4; ++n) {
            const int crow = row0 + wr * 64 + m * 16 + (lane >> 4) * 4;
            const int ccol = col0 + wc * 64 + n * 16 + (lane & 15);
            const float bias = gb[ccol];
            #pragma unroll
            for (int j = 0; j < 4; ++j) {
                const size_t idx = (size_t)(crow + j) * HD + ccol;
                const float fe = bf2f(featsB[idx]);
                const float mr = bf2f(memrB[idx]);
                const float pre = acc[m][n][j] + bias;
                const float g = 1.0f / (1.0f + __expf(-pre));
                out[idx] = fe + g * mr;
            }
        }
    }
}

// ---------------------------------------------------------------------------
extern "C" void kernel_launch(void* const* d_in, const int* in_sizes, int n_in,
                              void* d_out, int out_size, void* d_ws, size_t ws_size,
                              hipStream_t stream)
{
    const float* x   = (const float*)d_in[0];
    const float* sm  = (const float*)d_in[1];
    const float* pos = (const float*)d_in[2];
    const float* gw  = (const float*)d_in[3];
    const float* gb  = (const float*)d_in[4];
    float* out = (float*)d_out;

    u16* featsB = (u16*)d_ws;                       // 51200*1024 bf16
    u16* memrB  = featsB + (size_t)RTOT * HD;       // 51200*1024 bf16
    u16* gwB    = memrB + (size_t)RTOT * HD;        // 1024*2048 bf16

    k_cvt_w<<<dim3(1024), dim3(256), 0, stream>>>(gw, gwB);
    k_feats_mem<<<dim3(RTOT / 64), dim3(256), 0, stream>>>(x, sm, pos, featsB, memrB);
    k_gate_out<<<dim3(3200), dim3(256), 0, stream>>>(featsB, memrB, gwB, gb, out);
}

// Round 2
// 605.276 us; speedup vs baseline: 1.1709x; 1.1709x over previous
//
#include <hip/hip_runtime.h>
#include <cstdint>
#include <cstddef>

#define HD   1024
#define SEQL 200
#define MEMN 50
#define RTOT 51200   // 256 * 200
#define KP   128
#define PADK 136     // KP + 8 bf16 pad -> LDS row stride 272B (2-way, free)

typedef float  f4    __attribute__((ext_vector_type(4)));
typedef float  f32x4 __attribute__((ext_vector_type(4)));
typedef short  s16x8 __attribute__((ext_vector_type(8)));
typedef unsigned short u16;
typedef unsigned short u16x4 __attribute__((ext_vector_type(4)));

__device__ __forceinline__ u16 f2bf(float f) {
    unsigned u = __builtin_bit_cast(unsigned, f);
    u += 0x7FFFu + ((u >> 16) & 1u);          // RNE
    return (u16)(u >> 16);
}
__device__ __forceinline__ float bf2f(u16 h) {
    unsigned u = ((unsigned)h) << 16;
    return __builtin_bit_cast(float, u);
}

#define GLOAD_LDS16(g, l) __builtin_amdgcn_global_load_lds( \
    (const __attribute__((address_space(1))) unsigned int*)(g), \
    (__attribute__((address_space(3))) unsigned int*)(l), 16, 0, 0)

// ---------------------------------------------------------------------------
// K0a: gate_w f32 -> bf16 (layout preserved: [o][2048], K-contiguous)
// ---------------------------------------------------------------------------
__global__ __launch_bounds__(256) void k_cvt_w(const float* __restrict__ gw,
                                               u16* __restrict__ gwB)
{
    const size_t i = ((size_t)blockIdx.x * 256 + threadIdx.x) * 8;
    f4 v0 = *(const f4*)&gw[i];
    f4 v1 = *(const f4*)&gw[i + 4];
    u16x4 b0 = { f2bf(v0.x), f2bf(v0.y), f2bf(v0.z), f2bf(v0.w) };
    u16x4 b1 = { f2bf(v1.x), f2bf(v1.y), f2bf(v1.z), f2bf(v1.w) };
    *(u16x4*)&gwB[i]     = b0;
    *(u16x4*)&gwB[i + 4] = b1;
}

// ---------------------------------------------------------------------------
// K0b: spatial memory -> {memHi, memLo} [64][1024] bf16 (rows 50..63 zero)
//      and memT [1024][64] bf16 (hi only, transposed, zero-padded).
// ---------------------------------------------------------------------------
__global__ __launch_bounds__(256) void k_prep_mem(const float* __restrict__ sm,
                                                  u16* __restrict__ memHi,
                                                  u16* __restrict__ memLo,
                                                  u16* __restrict__ memT)
{
    const int idx = blockIdx.x * 256 + threadIdx.x;   // 16384 total
    const int m  = idx >> 8;
    const int h0 = (idx & 255) * 4;
    f4 v = {0.f, 0.f, 0.f, 0.f};
    if (m < MEMN) v = *(const f4*)&sm[(size_t)m * HD + h0];
    u16x4 hi = { f2bf(v.x), f2bf(v.y), f2bf(v.z), f2bf(v.w) };
    f4 hv = { bf2f(hi.x), bf2f(hi.y), bf2f(hi.z), bf2f(hi.w) };
    f4 lv = v - hv;
    u16x4 lo = { f2bf(lv.x), f2bf(lv.y), f2bf(lv.z), f2bf(lv.w) };
    *(u16x4*)&memHi[(size_t)m * HD + h0] = hi;
    *(u16x4*)&memLo[(size_t)m * HD + h0] = lo;
    memT[(size_t)(h0 + 0) * 64 + m] = hi.x;
    memT[(size_t)(h0 + 1) * 64 + m] = hi.y;
    memT[(size_t)(h0 + 2) * 64 + m] = hi.z;
    memT[(size_t)(h0 + 3) * 64 + m] = hi.w;
}

// ---------------------------------------------------------------------------
// K1: feats = x + pos (store bf16); sim via bf16x2-split MFMA; softmax;
//     mem_read via MFMA (store bf16). 64 rows/block, 4 waves, wave w owns
//     rows 16w..16w+15 (stages its own rows -> per-panel barrier only).
// ---------------------------------------------------------------------------
__global__ __launch_bounds__(256) void k_pre(
    const float* __restrict__ x, const float* __restrict__ pos,
    const u16* __restrict__ memHi, const u16* __restrict__ memLo,
    const u16* __restrict__ memT,
    u16* __restrict__ featsB, u16* __restrict__ memrB)
{
    __shared__ u16 fHi[64 * PADK];
    __shared__ u16 fLo[64 * PADK];
    __shared__ u16 wB[64 * 72];      // softmax weights bf16, row stride 144B

    const int tid  = threadIdx.x;
    const int r0   = blockIdx.x * 64;
    const int lane = tid & 63, w = tid >> 6;
    const int fr   = lane & 15;           // MFMA frag row/col within tile
    const int fk   = (lane >> 4) * 8;     // MFMA frag k offset
    const int jr   = (lane >> 4) * 4;     // C-frag row base

    const int srow = tid >> 2;            // staging row 0..63 (== wave's rows)
    const int scol = (tid & 3) * 4;
    const int prow = (r0 + srow) % SEQL;

    f32x4 acc[4] = {};                    // sim[16 rows][m = n*16 + fr]

    for (int kp = 0; kp < HD; kp += KP) {
        // ---- stage feats hi/lo into LDS, emit bf16 feats to global ----
        #pragma unroll
        for (int i = 0; i < 8; ++i) {
            const int c = scol + i * 16;
            f4 xv = *(const f4*)&x[(size_t)(r0 + srow) * HD + kp + c];
            f4 pv = *(const f4*)&pos[(size_t)prow * HD + kp + c];
            f4 fv = xv + pv;
            u16x4 hi = { f2bf(fv.x), f2bf(fv.y), f2bf(fv.z), f2bf(fv.w) };
            f4 hv = { bf2f(hi.x), bf2f(hi.y), bf2f(hi.z), bf2f(hi.w) };
            f4 lv = fv - hv;
            u16x4 lo = { f2bf(lv.x), f2bf(lv.y), f2bf(lv.z), f2bf(lv.w) };
            *(u16x4*)&fHi[srow * PADK + c] = hi;
            *(u16x4*)&fLo[srow * PADK + c] = lo;
            *(u16x4*)&featsB[(size_t)(r0 + srow) * HD + kp + c] = hi;
        }
        __syncthreads();

        // ---- sim MFMA: 3 split-passes, B-frags straight from L2 ----
        #pragma unroll
        for (int ks = 0; ks < KP / 32; ++ks) {
            const int kb = ks * 32 + fk;
            s16x8 aH = *(const s16x8*)&fHi[(16 * w + fr) * PADK + kb];
            s16x8 aL = *(const s16x8*)&fLo[(16 * w + fr) * PADK + kb];
            #pragma unroll
            for (int n = 0; n < 4; ++n) {
                const size_t mb = (size_t)(n * 16 + fr) * HD + kp + kb;
                s16x8 bH = *(const s16x8*)&memHi[mb];
                s16x8 bL = *(const s16x8*)&memLo[mb];
                acc[n] = __builtin_amdgcn_mfma_f32_16x16x32_bf16(aH, bH, acc[n], 0, 0, 0);
                acc[n] = __builtin_amdgcn_mfma_f32_16x16x32_bf16(aH, bL, acc[n], 0, 0, 0);
                acc[n] = __builtin_amdgcn_mfma_f32_16x16x32_bf16(aL, bH, acc[n], 0, 0, 0);
            }
        }
        __syncthreads();
    }

    // ---- softmax over m (50) in f32; lane holds rows jr+j, col n*16+fr ----
    #pragma unroll
    for (int j = 0; j < 4; ++j) {
        float v[4];
        float mx = -1e30f;
        #pragma unroll
        for (int n = 0; n < 4; ++n) {
            v[n] = acc[n][j];
            const int m = n * 16 + fr;
            if (m < MEMN) mx = fmaxf(mx, v[n]);
        }
        #pragma unroll
        for (int d = 1; d < 16; d <<= 1) mx = fmaxf(mx, __shfl_xor(mx, d));
        float e[4], s = 0.f;
        #pragma unroll
        for (int n = 0; n < 4; ++n) {
            const int m = n * 16 + fr;
            e[n] = (m < MEMN) ? __expf(v[n] - mx) : 0.f;
            s += e[n];
        }
        #pragma unroll
        for (int d = 1; d < 16; d <<= 1) s += __shfl_xor(s, d);
        const float inv = 1.f / s;
        const int rloc = 16 * w + jr + j;
        #pragma unroll
        for (int n = 0; n < 4; ++n)
            wB[rloc * 72 + n * 16 + fr] = f2bf(e[n] * inv);   // 0 for m>=50
    }

    // ---- mem_read = w @ mem via MFMA (K = 64, zero-padded) ----
    s16x8 aW[2];
    #pragma unroll
    for (int ks = 0; ks < 2; ++ks)
        aW[ks] = *(const s16x8*)&wB[(16 * w + fr) * 72 + ks * 32 + fk];

    for (int c0 = 0; c0 < HD; c0 += 128) {
        f32x4 a2[8] = {};
        #pragma unroll
        for (int ks = 0; ks < 2; ++ks) {
            #pragma unroll
            for (int nt = 0; nt < 8; ++nt) {
                const int h = c0 + nt * 16 + fr;
                s16x8 bT = *(const s16x8*)&memT[(size_t)h * 64 + ks * 32 + fk];
                a2[nt] = __builtin_amdgcn_mfma_f32_16x16x32_bf16(aW[ks], bT, a2[nt], 0, 0, 0);
            }
        }
        #pragma unroll
        for (int nt = 0; nt < 8; ++nt) {
            const int h = c0 + nt * 16 + fr;
            #pragma unroll
            for (int j = 0; j < 4; ++j) {
                const int r = r0 + 16 * w + jr + j;
                memrB[(size_t)r * HD + h] = f2bf(a2[nt][j]);
            }
        }
    }
}

// ---------------------------------------------------------------------------
// K2: gate GEMM (M=51200, N=1024, K=2048 concat) + sigmoid + residual out.
//     128x128 tile, BK=32, 4 waves; double-buffered LDS + counted vmcnt(4)
//     prefetch + raw s_barrier (no vmcnt(0) drain in main loop).
// ---------------------------------------------------------------------------
__global__ __launch_bounds__(256) void k_gate_out(
    const u16* __restrict__ featsB, const u16* __restrict__ memrB,
    const u16* __restrict__ gwB, const float* __restrict__ gb,
    float* __restrict__ out)
{
    __shared__ u16 As[2][128 * 32];
    __shared__ u16 Bs[2][128 * 32];

    const int tid = threadIdx.x;
    int bid = blockIdx.x;
    bid = (bid & 7) * 400 + (bid >> 3);      // XCD swizzle (3200 % 8 == 0)
    const int mt = bid >> 3, nt = bid & 7;
    const int row0 = mt * 128, col0 = nt * 128;
    const int lane = tid & 63, wave = tid >> 6;
    const int wr = wave >> 1, wc = wave & 1;

    f32x4 acc[4][4] = {};

    const int sr = tid >> 2;                 // staging row 0..63
    const int sc = (tid & 3) * 8;            // staging col (elements)

    auto stage = [&](int buf, int kt) {
        const u16* Asrc = (kt < 32) ? featsB : memrB;
        const int kcol = (kt & 31) * 32;
        GLOAD_LDS16(Asrc + (size_t)(row0 + sr) * HD + kcol + sc,      &As[buf][tid * 8]);
        GLOAD_LDS16(Asrc + (size_t)(row0 + 64 + sr) * HD + kcol + sc, &As[buf][2048 + tid * 8]);
        GLOAD_LDS16(gwB + (size_t)(col0 + sr) * 2048 + kt * 32 + sc,      &Bs[buf][tid * 8]);
        GLOAD_LDS16(gwB + (size_t)(col0 + 64 + sr) * 2048 + kt * 32 + sc, &Bs[buf][2048 + tid * 8]);
    };

    stage(0, 0);
    int cur = 0;
    const int fr = lane & 15, fk = (lane >> 4) * 8;

    for (int kt = 0; kt < 64; ++kt) {
        if (kt < 63) {
            stage(cur ^ 1, kt + 1);
            asm volatile("s_waitcnt vmcnt(4)" ::: "memory");   // cur's 4 done
        } else {
            asm volatile("s_waitcnt vmcnt(0)" ::: "memory");
        }
        __builtin_amdgcn_s_barrier();
        __builtin_amdgcn_sched_barrier(0);

        s16x8 aF[4], bF[4];
        #pragma unroll
        for (int m = 0; m < 4; ++m)
            aF[m] = *(const s16x8*)&As[cur][(wr * 64 + m * 16 + fr) * 32 + fk];
        #pragma unroll
        for (int n = 0; n < 4; ++n)
            bF[n] = *(const s16x8*)&Bs[cur][(wc * 64 + n * 16 + fr) * 32 + fk];
        #pragma unroll
        for (int m = 0; m < 4; ++m)
            #pragma unroll
            for (int n = 0; n < 4; ++n)
                acc[m][n] = __builtin_amdgcn_mfma_f32_16x16x32_bf16(
                    aF[m], bF[n], acc[m][n], 0, 0, 0);

        __builtin_amdgcn_sched_barrier(0);
        __builtin_amdgcn_s_barrier();
        cur ^= 1;
    }

    // epilogue: out = feats + sigmoid(acc + b) * mem_read
    #pragma unroll
    for (int m = 0; m < 4; ++m) {
        #pragma unroll
        for (int n = 0; n < 4; ++n) {
            const int crow = row0 + wr * 64 + m * 16 + (lane >> 4) * 4;
            const int ccol = col0 + wc * 64 + n * 16 + (lane & 15);
            const float bias = gb[ccol];
            #pragma unroll
            for (int j = 0; j < 4; ++j) {
                const size_t idx = (size_t)(crow + j) * HD + ccol;
                const float fe = bf2f(featsB[idx]);
                const float mr = bf2f(memrB[idx]);
                const float pre = acc[m][n][j] + bias;
                const float g = 1.0f / (1.0f + __expf(-pre));
                out[idx] = fe + g * mr;
            }
        }
    }
}

// ---------------------------------------------------------------------------
extern "C" void kernel_launch(void* const* d_in, const int* in_sizes, int n_in,
                              void* d_out, int out_size, void* d_ws, size_t ws_size,
                              hipStream_t stream)
{
    const float* x   = (const float*)d_in[0];
    const float* sm  = (const float*)d_in[1];
    const float* pos = (const float*)d_in[2];
    const float* gw  = (const float*)d_in[3];
    const float* gb  = (const float*)d_in[4];
    float* out = (float*)d_out;

    u16* featsB = (u16*)d_ws;                          // 51200*1024
    u16* memrB  = featsB + (size_t)RTOT * HD;          // 51200*1024
    u16* gwB    = memrB + (size_t)RTOT * HD;           // 1024*2048
    u16* memHi  = gwB + (size_t)HD * 2048;             // 64*1024
    u16* memLo  = memHi + 64 * HD;                     // 64*1024
    u16* memT   = memLo + 64 * HD;                     // 1024*64

    k_cvt_w<<<dim3(1024), dim3(256), 0, stream>>>(gw, gwB);
    k_prep_mem<<<dim3(64), dim3(256), 0, stream>>>(sm, memHi, memLo, memT);
    k_pre<<<dim3(RTOT / 64), dim3(256), 0, stream>>>(x, pos, memHi, memLo, memT,
                                                     featsB, memrB);
    k_gate_out<<<dim3(3200), dim3(256), 0, stream>>>(featsB, memrB, gwB, gb, out);
}